// Round 1
// baseline (2602.707 us; speedup 1.0000x reference)
//
#include <hip/hip_runtime.h>

#define NBq 16384
#define NXq 512
#define NUq 256
#define NYq 128
#define NQq 256
#define KP  1024   // P width: [x(512) | w(256) | u(256)]
#define AUGW 1536  // [E(512) | F(512) | B1(256) | B2(256)]

typedef __attribute__((ext_vector_type(8))) short short8;
typedef __attribute__((ext_vector_type(4))) float f32x4;

__device__ __forceinline__ ushort f2bf(float f) {
  uint x = __float_as_uint(f);
  x += 0x7FFFu + ((x >> 16) & 1u);   // RNE
  return (ushort)(x >> 16);
}

// ---------------- pack x,u -> P (bf16) ----------------
__global__ __launch_bounds__(256) void k_pack(const float* __restrict__ x,
                                              const float* __restrict__ u,
                                              ushort* __restrict__ P) {
  int idx = blockIdx.x * 256 + threadIdx.x;
  const int nx4 = NBq * NXq / 4;   // 2097152
  const int nu4 = NBq * NUq / 4;   // 1048576
  if (idx < nx4) {
    float4 v = *(const float4*)(x + (size_t)idx * 4);
    int row = idx >> 7, c4 = idx & 127;
    ushort4 h = { f2bf(v.x), f2bf(v.y), f2bf(v.z), f2bf(v.w) };
    *(ushort4*)(P + (size_t)row * KP + c4 * 4) = h;
  } else if (idx < nx4 + nu4) {
    int i = idx - nx4;
    float4 v = *(const float4*)(u + (size_t)i * 4);
    int row = i >> 6, c4 = i & 63;
    ushort4 h = { f2bf(v.x), f2bf(v.y), f2bf(v.z), f2bf(v.w) };
    *(ushort4*)(P + (size_t)row * KP + 768 + c4 * 4) = h;
  }
}

// ---------------- assemble augmented [E | F B1 B2] ----------------
__global__ __launch_bounds__(256) void k_aug(const float* __restrict__ E, const float* __restrict__ F,
                                             const float* __restrict__ B1, const float* __restrict__ B2,
                                             float* __restrict__ AUG) {
  int idx = blockIdx.x * 256 + threadIdx.x;   // < 512*1536
  int r = idx / AUGW, c = idx % AUGW;
  float v;
  if (c < 512)       v = E[r * 512 + c];
  else if (c < 1024) v = F[r * 512 + (c - 512)];
  else if (c < 1280) v = B1[r * 256 + (c - 1024)];
  else               v = B2[r * 256 + (c - 1280)];
  AUG[idx] = v;
}

// ---------------- blocked Gauss-Jordan: invert 64x64 diag block ----------------
__global__ __launch_bounds__(256) void k_invdiag(const float* __restrict__ AUG,
                                                 float* __restrict__ Dinv, int s) {
  __shared__ float M[64][130];
  __shared__ float mult[64];
  __shared__ float prcp;
  int tid = threadIdx.x;
  int s64 = s * 64;
  for (int i = tid; i < 64 * 64; i += 256) {
    int r = i >> 6, c = i & 63;
    M[r][c] = AUG[(size_t)(s64 + r) * AUGW + s64 + c];
    M[r][64 + c] = (r == c) ? 1.f : 0.f;
  }
  __syncthreads();
  for (int p = 0; p < 64; ++p) {
    if (tid == 0) prcp = 1.f / M[p][p];
    __syncthreads();
    for (int c = tid; c < 128; c += 256) M[p][c] *= prcp;
    __syncthreads();
    if (tid < 64) mult[tid] = (tid == p) ? 0.f : M[tid][p];
    __syncthreads();
    for (int i = tid; i < 64 * 128; i += 256) {
      int r = i >> 7, c = i & 127;
      if (r != p) M[r][c] = fmaf(-mult[r], M[p][c], M[r][c]);
    }
    __syncthreads();
  }
  for (int i = tid; i < 64 * 64; i += 256) {
    int r = i >> 6, c = i & 63;
    Dinv[r * 64 + c] = M[r][64 + c];
  }
}

// ---------------- GJ: scaled panel PB = Dinv @ AUG[pivot rows,:]; MC = multipliers ----------------
__global__ __launch_bounds__(256) void k_panel(const float* __restrict__ AUG, const float* __restrict__ Dinv,
                                               float* __restrict__ PB, float* __restrict__ MC, int s) {
  int idx = blockIdx.x * 256 + threadIdx.x;
  int s64 = s * 64;
  if (idx < 64 * AUGW) {
    int j = idx / AUGW, c = idx % AUGW;
    float acc = 0.f;
    for (int q = 0; q < 64; ++q)
      acc = fmaf(Dinv[j * 64 + q], AUG[(size_t)(s64 + q) * AUGW + c], acc);
    PB[j * AUGW + c] = acc;
  } else {
    int i = idx - 64 * AUGW;   // < 512*64
    int r = i >> 6, jj = i & 63;
    MC[i] = AUG[(size_t)r * AUGW + s64 + jj];
  }
}

// ---------------- GJ: eliminate (rank-64 update of AUG), pivot rows <- PB ----------------
__global__ __launch_bounds__(256) void k_eliminate(float* __restrict__ AUG, const float* __restrict__ PB,
                                                   const float* __restrict__ MC, int s) {
  __shared__ float sPB[64][65];
  __shared__ float sMC[64][65];
  int tid = threadIdx.x;
  int r0 = blockIdx.x * 64, c0 = blockIdx.y * 64;
  for (int i = tid; i < 64 * 64; i += 256) {
    int a = i >> 6, b = i & 63;
    sPB[a][b] = PB[a * AUGW + c0 + b];
    sMC[a][b] = MC[(r0 + a) * 64 + b];
  }
  __syncthreads();
  int cc = tid & 63, rg = tid >> 6;   // 4 row groups of 16
  if (blockIdx.x == (unsigned)s) {
    #pragma unroll
    for (int i = 0; i < 16; ++i) {
      int rr = rg * 16 + i;
      AUG[(size_t)(r0 + rr) * AUGW + c0 + cc] = sPB[rr][cc];
    }
  } else {
    #pragma unroll
    for (int i = 0; i < 16; ++i) {
      int rr = rg * 16 + i;
      float acc = AUG[(size_t)(r0 + rr) * AUGW + c0 + cc];
      #pragma unroll 8
      for (int j = 0; j < 64; ++j) acc = fmaf(-sMC[rr][j], sPB[j][cc], acc);
      AUG[(size_t)(r0 + rr) * AUGW + c0 + cc] = acc;
    }
  }
}

// ---------------- assemble weight matrices (fp32, converted during GEMM staging) ----------------
// Wfull [640][1024]: rows 0..511 -> G = E^{-1}[F|B1|B2] (k-order matches P: x,w,u)
//                    rows 512..639 -> [C2 | D21 | 0]
__global__ __launch_bounds__(256) void k_wfull(const float* __restrict__ AUG, const float* __restrict__ C2,
                                               const float* __restrict__ D21, float* __restrict__ W) {
  int idx = blockIdx.x * 256 + threadIdx.x;   // < 640*1024
  int r = idx >> 10, k = idx & 1023;
  float v;
  if (r < 512) v = AUG[(size_t)r * AUGW + 512 + k];
  else {
    int j = r - 512;
    if (k < 512)      v = C2[j * 512 + k];
    else if (k < 768) v = D21[j * 256 + (k - 512)];
    else              v = 0.f;
  }
  W[idx] = v;
}

// Wxu [256][1024]: [C1 | 0 | D12]
__global__ __launch_bounds__(256) void k_wxu(const float* __restrict__ C1, const float* __restrict__ D12,
                                             float* __restrict__ W) {
  int idx = blockIdx.x * 256 + threadIdx.x;   // < 256*1024
  int r = idx >> 10, k = idx & 1023;
  float v;
  if (k < 512)      v = C1[r * 512 + k];
  else if (k < 768) v = 0.f;
  else              v = D12[r * 256 + (k - 768)];
  W[idx] = v;
}

// ---------------- bf16 MFMA GEMM: out[m][n] = sum_k P[m][k] * W[n][k] ----------------
// BM=128, BN=128, BK=32, 256 threads (4 waves, 2x2 of 64x64 wave tiles)
template<bool SPLIT>
__global__ __launch_bounds__(256) void k_gemm(const ushort* __restrict__ P, const float* __restrict__ W,
                                              float* __restrict__ out) {
  __shared__ ushort sA[128 * 32];
  __shared__ ushort sB[128 * 32];
  int tid = threadIdx.x;
  int lane = tid & 63, wave = tid >> 6;
  int wm = wave & 1, wn = wave >> 1;
  int m0 = blockIdx.x * 128;
  int n0 = blockIdx.y * 128;
  int r16 = lane & 15, kq = lane >> 4;
  f32x4 acc[4][4] = {};
  for (int kb = 0; kb < KP / 32; ++kb) {
    #pragma unroll
    for (int j = 0; j < 2; ++j) {          // stage A: 128x32 bf16
      int i = tid + j * 256;
      int row = i >> 2, seg = i & 3;
      *(uint4*)(&sA[row * 32 + seg * 8]) =
          *(const uint4*)(P + (size_t)(m0 + row) * KP + kb * 32 + seg * 8);
    }
    #pragma unroll
    for (int j = 0; j < 4; ++j) {          // stage B: 128x32 fp32 -> bf16
      int i = tid + j * 256;
      int row = i >> 3, seg = i & 7;
      float4 v = *(const float4*)(W + (size_t)(n0 + row) * KP + kb * 32 + seg * 4);
      ushort4 h = { f2bf(v.x), f2bf(v.y), f2bf(v.z), f2bf(v.w) };
      *(ushort4*)(&sB[row * 32 + seg * 4]) = h;
    }
    __syncthreads();
    short8 af[4], bf[4];
    #pragma unroll
    for (int t = 0; t < 4; ++t) {
      af[t] = *(const short8*)(&sA[(wm * 64 + t * 16 + r16) * 32 + kq * 8]);
      bf[t] = *(const short8*)(&sB[(wn * 64 + t * 16 + r16) * 32 + kq * 8]);
    }
    #pragma unroll
    for (int mt = 0; mt < 4; ++mt)
      #pragma unroll
      for (int nt = 0; nt < 4; ++nt)
        acc[mt][nt] = __builtin_amdgcn_mfma_f32_16x16x32_bf16(af[mt], bf[nt], acc[mt][nt], 0, 0, 0);
    __syncthreads();
  }
  // epilogue: C/D layout col=lane&15, row=(lane>>4)*4+i  [m89/m91-verified]
  #pragma unroll
  for (int mt = 0; mt < 4; ++mt)
    #pragma unroll
    for (int nt = 0; nt < 4; ++nt)
      #pragma unroll
      for (int i = 0; i < 4; ++i) {
        int m = m0 + wm * 64 + mt * 16 + kq * 4 + i;
        int n = n0 + wn * 64 + nt * 16 + r16;
        float val = acc[mt][nt][i];
        if (SPLIT) {
          if (n < NXq) out[(size_t)m * NXq + n] = val;
          else out[(size_t)NBq * NXq + (size_t)m * NYq + (n - NXq)] = val;
        } else {
          out[(size_t)m * NQq + n] = val;
        }
      }
}

// ---------------- sequential tanh forward substitution ----------------
// 1 wave/block, lane = batch row; w lane-private in LDS (transposed float2 layout, conflict-free)
__global__ __launch_bounds__(64) void k_solve(const float* __restrict__ xu, const float* __restrict__ D11,
                                              const float* __restrict__ lam, const float* __restrict__ bv,
                                              ushort* __restrict__ P) {
  __shared__ float2 wt2[128][64];   // [j-pair][lane] = (w[2j], w[2j+1])  -- 64KB
  int lane = threadIdx.x;
  size_t r0 = (size_t)blockIdx.x * 64;
  #pragma unroll 4
  for (int i = lane; i < 128 * 64; i += 64) ((float2*)wt2)[i] = make_float2(0.f, 0.f);
  const float* xurow = xu + (r0 + lane) * NQq;
  for (int k = 0; k < NQq; ++k) {
    const float* drow = D11 + k * NQq;   // wave-uniform -> scalar loads
    float a = 0.f, b = 0.f;
    int jmax = (k + 1) >> 1;             // unwritten future slots are 0
    for (int j2 = 0; j2 < jmax; ++j2) {
      float2 w2 = wt2[j2][lane];
      a = fmaf(w2.x, drow[2 * j2], a);
      b = fmaf(w2.y, drow[2 * j2 + 1], b);
    }
    float v = (xurow[k] + a + b + bv[k]) / lam[k];
    float e = __expf(2.f * v);
    float t = 1.f - 2.f / (1.f + e);     // tanh; e->inf gives t=1, e->0 gives t=-1
    ((float*)&wt2[k >> 1][lane])[k & 1] = t;
  }
  // write w (bf16) into P cols 512..767
  ushort* prow = P + (r0 + lane) * KP + NXq;
  #pragma unroll 4
  for (int j2 = 0; j2 < 128; ++j2) {
    float2 w2 = wt2[j2][lane];
    uint pk = (uint)f2bf(w2.x) | ((uint)f2bf(w2.y) << 16);
    *(uint*)(prow + 2 * j2) = pk;
  }
}

extern "C" void kernel_launch(void* const* d_in, const int* in_sizes, int n_in,
                              void* d_out, int out_size, void* d_ws, size_t ws_size,
                              hipStream_t stream) {
  const float* x   = (const float*)d_in[0];
  const float* u   = (const float*)d_in[1];
  const float* F   = (const float*)d_in[2];
  const float* B1  = (const float*)d_in[3];
  const float* B2  = (const float*)d_in[4];
  const float* C1  = (const float*)d_in[5];
  const float* C2  = (const float*)d_in[6];
  const float* D11 = (const float*)d_in[7];
  const float* D12 = (const float*)d_in[8];
  const float* D21 = (const float*)d_in[9];
  const float* E   = (const float*)d_in[10];
  const float* lam = (const float*)d_in[11];
  const float* bv  = (const float*)d_in[12];

  char* ws = (char*)d_ws;
  ushort* P    = (ushort*)ws;                                   // 32 MB
  float* xu    = (float*)(ws + (size_t)(32u << 20));            // 16 MB
  float* AUG   = (float*)(ws + (size_t)(48u << 20));            // 3 MB
  float* Dinv  = (float*)(ws + (size_t)(52u << 20));            // 16 KB
  float* PB    = (float*)(ws + (size_t)(52u << 20) + (1u << 20)); // 384 KB
  float* MC    = (float*)(ws + (size_t)(52u << 20) + (2u << 20)); // 128 KB
  float* Wfull = (float*)(ws + (size_t)(56u << 20));            // 2.5 MB
  float* Wxu   = (float*)(ws + (size_t)(60u << 20));            // 1 MB
  float* out   = (float*)d_out;

  k_pack<<<12288, 256, 0, stream>>>(x, u, P);
  k_aug<<<3072, 256, 0, stream>>>(E, F, B1, B2, AUG);
  for (int s = 0; s < 8; ++s) {
    k_invdiag<<<1, 256, 0, stream>>>(AUG, Dinv, s);
    k_panel<<<512, 256, 0, stream>>>(AUG, Dinv, PB, MC, s);
    k_eliminate<<<dim3(8, 24), 256, 0, stream>>>(AUG, PB, MC, s);
  }
  k_wfull<<<2560, 256, 0, stream>>>(AUG, C2, D21, Wfull);
  k_wxu<<<1024, 256, 0, stream>>>(C1, D12, Wxu);
  k_gemm<false><<<dim3(128, 2), 256, 0, stream>>>(P, Wxu, xu);   // xu = x@C1^T + u@D12^T
  k_solve<<<256, 64, 0, stream>>>(xu, D11, lam, bv, P);          // w -> P[:,512:768]
  k_gemm<true><<<dim3(128, 5), 256, 0, stream>>>(P, Wfull, out); // dx, y
}

// Round 2
// 2137.855 us; speedup vs baseline: 1.2174x; 1.2174x over previous
//
#include <hip/hip_runtime.h>

#define NBq 16384
#define NXq 512
#define NUq 256
#define NYq 128
#define NQq 256
#define KP  1024   // P width: [x(512) | w(256) | u(256)]
#define AUGW 1536  // [E(512) | F(512) | B1(256) | B2(256)]

typedef __attribute__((ext_vector_type(8))) short short8;
typedef __attribute__((ext_vector_type(4))) float f32x4;

__device__ __forceinline__ ushort f2bf(float f) {
  uint x = __float_as_uint(f);
  x += 0x7FFFu + ((x >> 16) & 1u);   // RNE
  return (ushort)(x >> 16);
}

// ---------------- pack x,u -> P (bf16) ----------------
__global__ __launch_bounds__(256) void k_pack(const float* __restrict__ x,
                                              const float* __restrict__ u,
                                              ushort* __restrict__ P) {
  int idx = blockIdx.x * 256 + threadIdx.x;
  const int nx4 = NBq * NXq / 4;
  const int nu4 = NBq * NUq / 4;
  if (idx < nx4) {
    float4 v = *(const float4*)(x + (size_t)idx * 4);
    int row = idx >> 7, c4 = idx & 127;
    ushort4 h = { f2bf(v.x), f2bf(v.y), f2bf(v.z), f2bf(v.w) };
    *(ushort4*)(P + (size_t)row * KP + c4 * 4) = h;
  } else if (idx < nx4 + nu4) {
    int i = idx - nx4;
    float4 v = *(const float4*)(u + (size_t)i * 4);
    int row = i >> 6, c4 = i & 63;
    ushort4 h = { f2bf(v.x), f2bf(v.y), f2bf(v.z), f2bf(v.w) };
    *(ushort4*)(P + (size_t)row * KP + 768 + c4 * 4) = h;
  }
}

// ---------------- assemble augmented [E | F B1 B2] ----------------
__global__ __launch_bounds__(256) void k_aug(const float* __restrict__ E, const float* __restrict__ F,
                                             const float* __restrict__ B1, const float* __restrict__ B2,
                                             float* __restrict__ AUG) {
  int idx = blockIdx.x * 256 + threadIdx.x;
  int r = idx / AUGW, c = idx % AUGW;
  float v;
  if (c < 512)       v = E[r * 512 + c];
  else if (c < 1024) v = F[r * 512 + (c - 512)];
  else if (c < 1280) v = B1[r * 256 + (c - 1024)];
  else               v = B2[r * 256 + (c - 1280)];
  AUG[idx] = v;
}

// ---------------- blocked Gauss-Jordan: invert 64x64 diag block ----------------
__global__ __launch_bounds__(256) void k_invdiag(const float* __restrict__ AUG,
                                                 float* __restrict__ Dinv, int s) {
  __shared__ float M[64][130];
  __shared__ float mult[64];
  __shared__ float prcp;
  int tid = threadIdx.x;
  int s64 = s * 64;
  for (int i = tid; i < 64 * 64; i += 256) {
    int r = i >> 6, c = i & 63;
    M[r][c] = AUG[(size_t)(s64 + r) * AUGW + s64 + c];
    M[r][64 + c] = (r == c) ? 1.f : 0.f;
  }
  __syncthreads();
  for (int p = 0; p < 64; ++p) {
    if (tid == 0) prcp = 1.f / M[p][p];
    __syncthreads();
    for (int c = tid; c < 128; c += 256) M[p][c] *= prcp;
    __syncthreads();
    if (tid < 64) mult[tid] = (tid == p) ? 0.f : M[tid][p];
    __syncthreads();
    for (int i = tid; i < 64 * 128; i += 256) {
      int r = i >> 7, c = i & 127;
      if (r != p) M[r][c] = fmaf(-mult[r], M[p][c], M[r][c]);
    }
    __syncthreads();
  }
  for (int i = tid; i < 64 * 64; i += 256) {
    int r = i >> 6, c = i & 63;
    Dinv[r * 64 + c] = M[r][64 + c];
  }
}

// ---------------- GJ: scaled panel PB = Dinv @ AUG[pivot rows,:]; MC = multipliers ----------------
__global__ __launch_bounds__(256) void k_panel(const float* __restrict__ AUG, const float* __restrict__ Dinv,
                                               float* __restrict__ PB, float* __restrict__ MC, int s) {
  int idx = blockIdx.x * 256 + threadIdx.x;
  int s64 = s * 64;
  if (idx < 64 * AUGW) {
    int j = idx / AUGW, c = idx % AUGW;
    float acc = 0.f;
    #pragma unroll 8
    for (int q = 0; q < 64; ++q)
      acc = fmaf(Dinv[j * 64 + q], AUG[(size_t)(s64 + q) * AUGW + c], acc);
    PB[j * AUGW + c] = acc;
  } else {
    int i = idx - 64 * AUGW;
    int r = i >> 6, jj = i & 63;
    MC[i] = AUG[(size_t)r * AUGW + s64 + jj];
  }
}

// ---------------- GJ: eliminate (rank-64 update of AUG), pivot rows <- PB ----------------
__global__ __launch_bounds__(256) void k_eliminate(float* __restrict__ AUG, const float* __restrict__ PB,
                                                   const float* __restrict__ MC, int s) {
  __shared__ float sPB[64][65];
  __shared__ float sMC[64][65];
  int tid = threadIdx.x;
  int r0 = blockIdx.x * 64, c0 = blockIdx.y * 64;
  for (int i = tid; i < 64 * 64; i += 256) {
    int a = i >> 6, b = i & 63;
    sPB[a][b] = PB[a * AUGW + c0 + b];
    sMC[a][b] = MC[(r0 + a) * 64 + b];
  }
  __syncthreads();
  int cc = tid & 63, rg = tid >> 6;
  if (blockIdx.x == (unsigned)s) {
    #pragma unroll
    for (int i = 0; i < 16; ++i) {
      int rr = rg * 16 + i;
      AUG[(size_t)(r0 + rr) * AUGW + c0 + cc] = sPB[rr][cc];
    }
  } else {
    #pragma unroll
    for (int i = 0; i < 16; ++i) {
      int rr = rg * 16 + i;
      float acc = AUG[(size_t)(r0 + rr) * AUGW + c0 + cc];
      #pragma unroll 8
      for (int j = 0; j < 64; ++j) acc = fmaf(-sMC[rr][j], sPB[j][cc], acc);
      AUG[(size_t)(r0 + rr) * AUGW + c0 + cc] = acc;
    }
  }
}

// ---------------- assemble weight matrices (pre-converted bf16) ----------------
// Wfull [640][1024]: rows 0..511 -> G = E^{-1}[F|B1|B2]; rows 512..639 -> [C2 | D21 | 0]
__global__ __launch_bounds__(256) void k_wfull(const float* __restrict__ AUG, const float* __restrict__ C2,
                                               const float* __restrict__ D21, ushort* __restrict__ W) {
  int idx = blockIdx.x * 256 + threadIdx.x;
  int r = idx >> 10, k = idx & 1023;
  float v;
  if (r < 512) v = AUG[(size_t)r * AUGW + 512 + k];
  else {
    int j = r - 512;
    if (k < 512)      v = C2[j * 512 + k];
    else if (k < 768) v = D21[j * 256 + (k - 512)];
    else              v = 0.f;
  }
  W[idx] = f2bf(v);
}

// Wxu [256][1024]: [C1 | 0 | D12]
__global__ __launch_bounds__(256) void k_wxu(const float* __restrict__ C1, const float* __restrict__ D12,
                                             ushort* __restrict__ W) {
  int idx = blockIdx.x * 256 + threadIdx.x;
  int r = idx >> 10, k = idx & 1023;
  float v;
  if (k < 512)      v = C1[r * 512 + k];
  else if (k < 768) v = 0.f;
  else              v = D12[r * 256 + (k - 768)];
  W[idx] = f2bf(v);
}

// ---------------- D11 -> bf16 ----------------
__global__ __launch_bounds__(256) void k_d11cvt(const float* __restrict__ D11, ushort* __restrict__ B) {
  int idx = blockIdx.x * 256 + threadIdx.x;   // 65536
  B[idx] = f2bf(D11[idx]);
}

// ---------------- bf16 MFMA GEMM: out[m][n] = sum_k P[m][k] * W[n][k] ----------------
template<bool SPLIT>
__global__ __launch_bounds__(256) void k_gemm(const ushort* __restrict__ P, const ushort* __restrict__ W,
                                              float* __restrict__ out) {
  __shared__ ushort sA[128 * 32];
  __shared__ ushort sB[128 * 32];
  int tid = threadIdx.x;
  int lane = tid & 63, wave = tid >> 6;
  int wm = wave & 1, wn = wave >> 1;
  int m0 = blockIdx.x * 128;
  int n0 = blockIdx.y * 128;
  int r16 = lane & 15, kq = lane >> 4;
  f32x4 acc[4][4] = {};
  for (int kb = 0; kb < KP / 32; ++kb) {
    #pragma unroll
    for (int j = 0; j < 2; ++j) {          // stage A: 128x32 bf16
      int i = tid + j * 256;
      int row = i >> 2, seg = i & 3;
      *(uint4*)(&sA[row * 32 + seg * 8]) =
          *(const uint4*)(P + (size_t)(m0 + row) * KP + kb * 32 + seg * 8);
    }
    #pragma unroll
    for (int j = 0; j < 2; ++j) {          // stage B: 128x32 bf16
      int i = tid + j * 256;
      int row = i >> 2, seg = i & 3;
      *(uint4*)(&sB[row * 32 + seg * 8]) =
          *(const uint4*)(W + (size_t)(n0 + row) * KP + kb * 32 + seg * 8);
    }
    __syncthreads();
    short8 af[4], bf[4];
    #pragma unroll
    for (int t = 0; t < 4; ++t) {
      af[t] = *(const short8*)(&sA[(wm * 64 + t * 16 + r16) * 32 + kq * 8]);
      bf[t] = *(const short8*)(&sB[(wn * 64 + t * 16 + r16) * 32 + kq * 8]);
    }
    #pragma unroll
    for (int mt = 0; mt < 4; ++mt)
      #pragma unroll
      for (int nt = 0; nt < 4; ++nt)
        acc[mt][nt] = __builtin_amdgcn_mfma_f32_16x16x32_bf16(af[mt], bf[nt], acc[mt][nt], 0, 0, 0);
    __syncthreads();
  }
  #pragma unroll
  for (int mt = 0; mt < 4; ++mt)
    #pragma unroll
    for (int nt = 0; nt < 4; ++nt)
      #pragma unroll
      for (int i = 0; i < 4; ++i) {
        int m = m0 + wm * 64 + mt * 16 + kq * 4 + i;
        int n = n0 + wn * 64 + nt * 16 + r16;
        float val = acc[mt][nt][i];
        if (SPLIT) {
          if (n < NXq) out[(size_t)m * NXq + n] = val;
          else out[(size_t)NBq * NXq + (size_t)m * NYq + (n - NXq)] = val;
        } else {
          out[(size_t)m * NQq + n] = val;
        }
      }
}

// ---------------- MFMA-blocked tanh forward substitution ----------------
// 256 blocks x 256 thr; each wave owns 16 batch rows independently.
// w held as bf16 A-fragments in regs (zero-init => over-spanning K chunks exact);
// cross-tile prefix via 16x16x32 bf16 MFMA; in-tile 16 sequential steps with
// __shfl broadcast (fp32-exact in-tile updates).
#define WSTRIDE 264

template<int t>
__device__ __forceinline__ void do_tile(const float* __restrict__ xu,
                                        const float* __restrict__ D11,
                                        const ushort* __restrict__ D11B,
                                        const float* __restrict__ lam,
                                        const float* __restrict__ bv,
                                        ushort* wb, float (*d11t)[17],
                                        short8 (&whiF)[8], int tid, int lane,
                                        int col, int quad, int r0w) {
  constexpr int kt = t * 16;
  constexpr int cmax = (t + 1) >> 1;
  // stage in-tile 16x16 D11 block (block-shared)
  __syncthreads();
  d11t[tid >> 4][tid & 15] = D11[(size_t)(kt + (tid >> 4)) * NQq + kt + (tid & 15)];
  __syncthreads();
  // acc init = xu tile in C-layout (row m = quad*4+i, col = k-in-tile)
  f32x4 acc;
  #pragma unroll
  for (int i = 0; i < 4; ++i)
    acc[i] = xu[(size_t)(r0w + quad * 4 + i) * NQq + kt + col];
  // cross-tile prefix: acc += w[:, :16t] @ D11[kt+col, :]^T
  #pragma unroll
  for (int c = 0; c < cmax; ++c) {
    short8 bh = *(const short8*)(D11B + (size_t)(kt + col) * NQq + c * 32 + quad * 8);
    acc = __builtin_amdgcn_mfma_f32_16x16x32_bf16(whiF[c], bh, acc, 0, 0, 0);
  }
  float rl = 1.0f / lam[kt + col];
  float bvrl = bv[kt + col] * rl;
  // 16 sequential steps
  for (int n = 0; n < 16; ++n) {
    float dv = d11t[col][n];
    float v0 = fmaf(acc[0], rl, bvrl);
    float v1 = fmaf(acc[1], rl, bvrl);
    float v2 = fmaf(acc[2], rl, bvrl);
    float v3 = fmaf(acc[3], rl, bvrl);
    float w0 = fmaf(-2.f, __builtin_amdgcn_rcpf(1.f + __expf(2.f * v0)), 1.f);
    float w1 = fmaf(-2.f, __builtin_amdgcn_rcpf(1.f + __expf(2.f * v1)), 1.f);
    float w2 = fmaf(-2.f, __builtin_amdgcn_rcpf(1.f + __expf(2.f * v2)), 1.f);
    float w3 = fmaf(-2.f, __builtin_amdgcn_rcpf(1.f + __expf(2.f * v3)), 1.f);
    if (col == n) {                         // writer lanes: persist bf16 w
      wb[(quad * 4 + 0) * WSTRIDE + kt + n] = f2bf(w0);
      wb[(quad * 4 + 1) * WSTRIDE + kt + n] = f2bf(w1);
      wb[(quad * 4 + 2) * WSTRIDE + kt + n] = f2bf(w2);
      wb[(quad * 4 + 3) * WSTRIDE + kt + n] = f2bf(w3);
    }
    int src = (lane & 48) | n;              // broadcast fp32 w along cols
    float b0 = __shfl(w0, src);
    float b1 = __shfl(w1, src);
    float b2 = __shfl(w2, src);
    float b3 = __shfl(w3, src);
    if (col > n) {
      acc[0] = fmaf(b0, dv, acc[0]);
      acc[1] = fmaf(b1, dv, acc[1]);
      acc[2] = fmaf(b2, dv, acc[2]);
      acc[3] = fmaf(b3, dv, acc[3]);
    }
  }
  // reload this tile's w into the A-fragment chunk it belongs to
  if ((quad >> 1) == (t & 1)) {
    constexpr int c = t >> 1;
    whiF[c] = *(const short8*)(wb + (lane & 15) * WSTRIDE + c * 32 + quad * 8);
  }
}

__global__ __launch_bounds__(256) void k_solve(const float* __restrict__ xu,
                                               const float* __restrict__ D11,
                                               const ushort* __restrict__ D11B,
                                               const float* __restrict__ lam,
                                               const float* __restrict__ bv,
                                               ushort* __restrict__ P) {
  __shared__ ushort wB[4][16 * WSTRIDE];   // per-wave bf16 w, 33.8 KB
  __shared__ float d11t[16][17];           // in-tile D11 block, 1.1 KB
  const int tid = threadIdx.x;
  const int wave = tid >> 6, lane = tid & 63;
  const int col = lane & 15, quad = lane >> 4;
  const int r0w = blockIdx.x * 64 + wave * 16;
  ushort* wb = &wB[wave][0];
  short8 whiF[8] = {};                     // w A-frags, zero-init

  do_tile<0>(xu, D11, D11B, lam, bv, wb, d11t, whiF, tid, lane, col, quad, r0w);
  do_tile<1>(xu, D11, D11B, lam, bv, wb, d11t, whiF, tid, lane, col, quad, r0w);
  do_tile<2>(xu, D11, D11B, lam, bv, wb, d11t, whiF, tid, lane, col, quad, r0w);
  do_tile<3>(xu, D11, D11B, lam, bv, wb, d11t, whiF, tid, lane, col, quad, r0w);
  do_tile<4>(xu, D11, D11B, lam, bv, wb, d11t, whiF, tid, lane, col, quad, r0w);
  do_tile<5>(xu, D11, D11B, lam, bv, wb, d11t, whiF, tid, lane, col, quad, r0w);
  do_tile<6>(xu, D11, D11B, lam, bv, wb, d11t, whiF, tid, lane, col, quad, r0w);
  do_tile<7>(xu, D11, D11B, lam, bv, wb, d11t, whiF, tid, lane, col, quad, r0w);
  do_tile<8>(xu, D11, D11B, lam, bv, wb, d11t, whiF, tid, lane, col, quad, r0w);
  do_tile<9>(xu, D11, D11B, lam, bv, wb, d11t, whiF, tid, lane, col, quad, r0w);
  do_tile<10>(xu, D11, D11B, lam, bv, wb, d11t, whiF, tid, lane, col, quad, r0w);
  do_tile<11>(xu, D11, D11B, lam, bv, wb, d11t, whiF, tid, lane, col, quad, r0w);
  do_tile<12>(xu, D11, D11B, lam, bv, wb, d11t, whiF, tid, lane, col, quad, r0w);
  do_tile<13>(xu, D11, D11B, lam, bv, wb, d11t, whiF, tid, lane, col, quad, r0w);
  do_tile<14>(xu, D11, D11B, lam, bv, wb, d11t, whiF, tid, lane, col, quad, r0w);
  do_tile<15>(xu, D11, D11B, lam, bv, wb, d11t, whiF, tid, lane, col, quad, r0w);

  // write w rows (bf16) to P cols 512..767 (coalesced 16B stores)
  #pragma unroll
  for (int it = 0; it < 8; ++it) {
    int f = it * 64 + lane;
    int m = f >> 5, k8 = f & 31;
    uint4 v = *(const uint4*)(wb + m * WSTRIDE + k8 * 8);
    *(uint4*)(P + (size_t)(r0w + m) * KP + NXq + k8 * 8) = v;
  }
}

extern "C" void kernel_launch(void* const* d_in, const int* in_sizes, int n_in,
                              void* d_out, int out_size, void* d_ws, size_t ws_size,
                              hipStream_t stream) {
  const float* x   = (const float*)d_in[0];
  const float* u   = (const float*)d_in[1];
  const float* F   = (const float*)d_in[2];
  const float* B1  = (const float*)d_in[3];
  const float* B2  = (const float*)d_in[4];
  const float* C1  = (const float*)d_in[5];
  const float* C2  = (const float*)d_in[6];
  const float* D11 = (const float*)d_in[7];
  const float* D12 = (const float*)d_in[8];
  const float* D21 = (const float*)d_in[9];
  const float* E   = (const float*)d_in[10];
  const float* lam = (const float*)d_in[11];
  const float* bv  = (const float*)d_in[12];

  char* ws = (char*)d_ws;
  ushort* P    = (ushort*)ws;                                     // 32 MB
  float* xu    = (float*)(ws + (size_t)(32u << 20));              // 16 MB
  float* AUG   = (float*)(ws + (size_t)(48u << 20));              // 3 MB
  float* Dinv  = (float*)(ws + (size_t)(52u << 20));              // 16 KB
  float* PB    = (float*)(ws + (size_t)(52u << 20) + (1u << 20)); // 384 KB
  float* MC    = (float*)(ws + (size_t)(52u << 20) + (2u << 20)); // 128 KB
  ushort* Wfull = (ushort*)(ws + (size_t)(56u << 20));            // 1.25 MB bf16
  ushort* Wxu   = (ushort*)(ws + (size_t)(58u << 20));            // 0.5 MB bf16
  ushort* D11B  = (ushort*)(ws + (size_t)(59u << 20));            // 128 KB bf16
  float* out   = (float*)d_out;

  k_pack<<<12288, 256, 0, stream>>>(x, u, P);
  k_aug<<<3072, 256, 0, stream>>>(E, F, B1, B2, AUG);
  for (int s = 0; s < 8; ++s) {
    k_invdiag<<<1, 256, 0, stream>>>(AUG, Dinv, s);
    k_panel<<<512, 256, 0, stream>>>(AUG, Dinv, PB, MC, s);
    k_eliminate<<<dim3(8, 24), 256, 0, stream>>>(AUG, PB, MC, s);
  }
  k_wfull<<<2560, 256, 0, stream>>>(AUG, C2, D21, Wfull);
  k_wxu<<<1024, 256, 0, stream>>>(C1, D12, Wxu);
  k_d11cvt<<<256, 256, 0, stream>>>(D11, D11B);
  k_gemm<false><<<dim3(128, 2), 256, 0, stream>>>(P, Wxu, xu);    // xu = x@C1^T + u@D12^T
  k_solve<<<256, 256, 0, stream>>>(xu, D11, D11B, lam, bv, P);    // w -> P[:,512:768]
  k_gemm<true><<<dim3(128, 5), 256, 0, stream>>>(P, Wfull, out);  // dx, y
}

// Round 3
// 805.376 us; speedup vs baseline: 3.2317x; 2.6545x over previous
//
#include <hip/hip_runtime.h>

#define NBq 16384
#define NXq 512
#define NUq 256
#define NYq 128
#define NQq 256
#define KP  1024   // P width: [x(512) | w(256) | u(256)]
#define AUGW 1536  // [E(512) | F(512) | B1(256) | B2(256)]

typedef __attribute__((ext_vector_type(8))) short short8;
typedef __attribute__((ext_vector_type(4))) float f32x4;

__device__ __forceinline__ ushort f2bf(float f) {
  uint x = __float_as_uint(f);
  x += 0x7FFFu + ((x >> 16) & 1u);   // RNE
  return (ushort)(x >> 16);
}

// ---------------- fused prep: pack x,u -> P ; AUG ; Wxu ; D11B ; Wfull static rows ----------------
__global__ __launch_bounds__(256) void k_prep(const float* __restrict__ x, const float* __restrict__ u,
                                              const float* __restrict__ E, const float* __restrict__ F,
                                              const float* __restrict__ B1, const float* __restrict__ B2,
                                              const float* __restrict__ C1, const float* __restrict__ C2,
                                              const float* __restrict__ D11, const float* __restrict__ D12,
                                              const float* __restrict__ D21,
                                              ushort* __restrict__ P, float* __restrict__ AUG,
                                              ushort* __restrict__ Wxu, ushort* __restrict__ D11B,
                                              ushort* __restrict__ Wfull) {
  int b = blockIdx.x, tid = threadIdx.x;
  if (b < 12288) {                       // pack x,u (float4 -> bf16x4)
    int idx = b * 256 + tid;
    const int nx4 = NBq * NXq / 4;
    if (idx < nx4) {
      float4 v = *(const float4*)(x + (size_t)idx * 4);
      int row = idx >> 7, c4 = idx & 127;
      ushort4 h = { f2bf(v.x), f2bf(v.y), f2bf(v.z), f2bf(v.w) };
      *(ushort4*)(P + (size_t)row * KP + c4 * 4) = h;
    } else {
      int i = idx - nx4;
      float4 v = *(const float4*)(u + (size_t)i * 4);
      int row = i >> 6, c4 = i & 63;
      ushort4 h = { f2bf(v.x), f2bf(v.y), f2bf(v.z), f2bf(v.w) };
      *(ushort4*)(P + (size_t)row * KP + 768 + c4 * 4) = h;
    }
  } else if (b < 15360) {                // AUG = [E | F B1 B2]
    int idx = (b - 12288) * 256 + tid;
    int r = idx / AUGW, c = idx % AUGW;
    float v;
    if (c < 512)       v = E[r * 512 + c];
    else if (c < 1024) v = F[r * 512 + (c - 512)];
    else if (c < 1280) v = B1[r * 256 + (c - 1024)];
    else               v = B2[r * 256 + (c - 1280)];
    AUG[idx] = v;
  } else if (b < 16384) {                // Wxu = [C1 | 0 | D12] bf16
    int idx = (b - 15360) * 256 + tid;
    int r = idx >> 10, k = idx & 1023;
    float v;
    if (k < 512)      v = C1[r * 512 + k];
    else if (k < 768) v = 0.f;
    else              v = D12[r * 256 + (k - 768)];
    Wxu[idx] = f2bf(v);
  } else if (b < 16640) {                // D11 -> bf16
    int idx = (b - 16384) * 256 + tid;
    D11B[idx] = f2bf(D11[idx]);
  } else {                               // Wfull rows 512..639 = [C2 | D21 | 0]
    int idx = (b - 16640) * 256 + tid;   // < 131072
    int j = idx >> 10, k = idx & 1023;
    float v;
    if (k < 512)      v = C2[j * 512 + k];
    else if (k < 768) v = D21[j * 256 + (k - 512)];
    else              v = 0.f;
    Wfull[(size_t)(512 + j) * KP + k] = f2bf(v);
  }
}

// ---------------- fused blocked Gauss-Jordan step (ping-pong) ----------------
// grid dim3(8, 23-s): r-tile = blockIdx.x, c-tile = s+1+blockIdx.y.
// Each block: invert pivot 64x64 in LDS (redundant, wall-parallel), PB = Dinv@panel,
// out = Ain - MC@PB (pivot-row tile: out = PB). Last step writes Wfull bf16 directly.
__global__ __launch_bounds__(256) void k_gj(const float* __restrict__ Ain, float* __restrict__ Aout,
                                            ushort* __restrict__ Wfull, int s, int last) {
  __shared__ float M[64][130];
  __shared__ float sP[64][65];
  __shared__ float sMC[64][65];
  const int tid = threadIdx.x;
  const int s64 = s * 64, r0 = blockIdx.x * 64, c0 = (s + 1 + blockIdx.y) * 64;
  // stage everything (independent loads)
  float av[16];
  {
    int r2 = tid >> 2, cq = (tid & 3) * 16;
    #pragma unroll
    for (int c = 0; c < 16; ++c)
      av[c] = Ain[(size_t)(r0 + r2) * AUGW + c0 + cq + c];
  }
  for (int i = tid; i < 64 * 64; i += 256) {
    int r = i >> 6, c = i & 63;
    M[r][c] = Ain[(size_t)(s64 + r) * AUGW + s64 + c];
    M[r][64 + c] = (r == c) ? 1.f : 0.f;
    sP[r][c] = Ain[(size_t)(s64 + r) * AUGW + c0 + c];
    sMC[r][c] = Ain[(size_t)(r0 + r) * AUGW + s64 + c];
  }
  __syncthreads();
  // in-LDS GJ inversion of M (2 barriers/pivot); thread owns row rr, col-half ch
  {
    int rr = tid & 63, ch = (tid >> 6) * 32;
    for (int p = 0; p < 64; ++p) {
      float prcp = 1.f / M[p][p];
      float mult = (rr == p) ? 0.f : M[rr][p] * prcp;
      float prow[32];
      #pragma unroll
      for (int c = 0; c < 32; ++c) prow[c] = M[p][ch + c];
      __syncthreads();
      if (rr == p) {
        #pragma unroll
        for (int c = 0; c < 32; ++c) M[p][ch + c] = prow[c] * prcp;
      } else {
        #pragma unroll
        for (int c = 0; c < 32; ++c) M[rr][ch + c] = fmaf(-mult, prow[c], M[rr][ch + c]);
      }
      __syncthreads();
    }
  }
  // PB = Dinv @ sP  (Dinv = M[:,64:128]); thread -> row r2, 16-col group cq
  const int r2 = tid >> 2, cq = (tid & 3) * 16;
  float pb[16] = {};
  #pragma unroll 8
  for (int q = 0; q < 64; ++q) {
    float dv = M[r2][64 + q];
    #pragma unroll
    for (int c = 0; c < 16; ++c) pb[c] = fmaf(dv, sP[q][cq + c], pb[c]);
  }
  __syncthreads();
  #pragma unroll
  for (int c = 0; c < 16; ++c) sP[r2][cq + c] = pb[c];
  __syncthreads();
  // out tile
  float o[16];
  if (blockIdx.x == (unsigned)s) {
    #pragma unroll
    for (int c = 0; c < 16; ++c) o[c] = sP[r2][cq + c];
  } else {
    #pragma unroll
    for (int c = 0; c < 16; ++c) o[c] = av[c];
    #pragma unroll 8
    for (int q = 0; q < 64; ++q) {
      float mc = sMC[r2][q];
      #pragma unroll
      for (int c = 0; c < 16; ++c) o[c] = fmaf(-mc, sP[q][cq + c], o[c]);
    }
  }
  if (last) {                       // G rows of Wfull (c0 >= 512 at s=7)
    int k0 = c0 - 512 + cq;
    #pragma unroll
    for (int c = 0; c < 16; c += 4) {
      ushort4 h = { f2bf(o[c]), f2bf(o[c+1]), f2bf(o[c+2]), f2bf(o[c+3]) };
      *(ushort4*)(Wfull + (size_t)(r0 + r2) * KP + k0 + c) = h;
    }
  } else {
    #pragma unroll
    for (int c = 0; c < 16; c += 4)
      *(float4*)(Aout + (size_t)(r0 + r2) * AUGW + c0 + cq + c) =
          make_float4(o[c], o[c+1], o[c+2], o[c+3]);
  }
}

// ---------------- bf16 MFMA GEMM: out[m][n] = sum_k P[m][k] * W[n][k] ----------------
template<bool SPLIT>
__global__ __launch_bounds__(256) void k_gemm(const ushort* __restrict__ P, const ushort* __restrict__ W,
                                              float* __restrict__ out) {
  __shared__ ushort sA[128 * 32];
  __shared__ ushort sB[128 * 32];
  int tid = threadIdx.x;
  int lane = tid & 63, wave = tid >> 6;
  int wm = wave & 1, wn = wave >> 1;
  int m0 = blockIdx.x * 128;
  int n0 = blockIdx.y * 128;
  int r16 = lane & 15, kq = lane >> 4;
  f32x4 acc[4][4] = {};
  for (int kb = 0; kb < KP / 32; ++kb) {
    #pragma unroll
    for (int j = 0; j < 2; ++j) {
      int i = tid + j * 256;
      int row = i >> 2, seg = i & 3;
      *(uint4*)(&sA[row * 32 + seg * 8]) =
          *(const uint4*)(P + (size_t)(m0 + row) * KP + kb * 32 + seg * 8);
      *(uint4*)(&sB[row * 32 + seg * 8]) =
          *(const uint4*)(W + (size_t)(n0 + row) * KP + kb * 32 + seg * 8);
    }
    __syncthreads();
    short8 af[4], bf[4];
    #pragma unroll
    for (int t = 0; t < 4; ++t) {
      af[t] = *(const short8*)(&sA[(wm * 64 + t * 16 + r16) * 32 + kq * 8]);
      bf[t] = *(const short8*)(&sB[(wn * 64 + t * 16 + r16) * 32 + kq * 8]);
    }
    #pragma unroll
    for (int mt = 0; mt < 4; ++mt)
      #pragma unroll
      for (int nt = 0; nt < 4; ++nt)
        acc[mt][nt] = __builtin_amdgcn_mfma_f32_16x16x32_bf16(af[mt], bf[nt], acc[mt][nt], 0, 0, 0);
    __syncthreads();
  }
  #pragma unroll
  for (int mt = 0; mt < 4; ++mt)
    #pragma unroll
    for (int nt = 0; nt < 4; ++nt)
      #pragma unroll
      for (int i = 0; i < 4; ++i) {
        int m = m0 + wm * 64 + mt * 16 + kq * 4 + i;
        int n = n0 + wn * 64 + nt * 16 + r16;
        float val = acc[mt][nt][i];
        if (SPLIT) {
          if (n < NXq) out[(size_t)m * NXq + n] = val;
          else out[(size_t)NBq * NXq + (size_t)m * NYq + (n - NXq)] = val;
        } else {
          out[(size_t)m * NQq + n] = val;
        }
      }
}

// ---------------- MFMA-blocked tanh forward substitution (barrier-free main loop) ----------------
#define WSTRIDE 264

struct Pre {
  f32x4 xuv;
  short8 b[8];
  float rl, bvrl;
};

template<int t>
__device__ __forceinline__ void tile_loads(const float* __restrict__ xu,
                                           const ushort* __restrict__ D11B,
                                           const float* __restrict__ lam,
                                           const float* __restrict__ bv,
                                           int col, int quad, int r0w, Pre& pre) {
  constexpr int kt = t * 16;
  constexpr int cmax = (t + 1) >> 1;
  #pragma unroll
  for (int i = 0; i < 4; ++i)
    pre.xuv[i] = xu[(size_t)(r0w + quad * 4 + i) * NQq + kt + col];
  #pragma unroll
  for (int c = 0; c < cmax; ++c)
    pre.b[c] = *(const short8*)(D11B + (size_t)(kt + col) * NQq + c * 32 + quad * 8);
  float l = lam[kt + col];
  pre.rl = 1.0f / l;
  pre.bvrl = bv[kt + col] * pre.rl;
}

template<int t>
__device__ __forceinline__ void do_tile(const float* __restrict__ xu,
                                        const ushort* __restrict__ D11B,
                                        const float* __restrict__ lam,
                                        const float* __restrict__ bv,
                                        ushort* wb, const float (*d11diag)[16][17],
                                        short8 (&whiF)[8], int lane, int col, int quad,
                                        int r0w, Pre& cur, Pre& nxt) {
  constexpr int kt = t * 16;
  constexpr int cmax = (t + 1) >> 1;
  // prefetch next tile's data (off critical path; covered by vmcnt during chain)
  if constexpr (t < 15)
    tile_loads<t + 1>(xu, D11B, lam, bv, col, quad, r0w, nxt);
  // cross-tile prefix via MFMA
  f32x4 acc = cur.xuv;
  #pragma unroll
  for (int c = 0; c < cmax; ++c)
    acc = __builtin_amdgcn_mfma_f32_16x16x32_bf16(whiF[c], cur.b[c], acc, 0, 0, 0);
  const float rl = cur.rl, bvrl = cur.bvrl;
  float w0r = 0.f, w1r = 0.f, w2r = 0.f, w3r = 0.f;   // writer-lane stash (off-chain)
  #pragma unroll
  for (int n = 0; n < 16; ++n) {
    float dv = d11diag[t][col][n];
    float v0 = fmaf(acc[0], rl, bvrl);
    float v1 = fmaf(acc[1], rl, bvrl);
    float v2 = fmaf(acc[2], rl, bvrl);
    float v3 = fmaf(acc[3], rl, bvrl);
    float w0 = fmaf(-2.f, __builtin_amdgcn_rcpf(1.f + __expf(2.f * v0)), 1.f);
    float w1 = fmaf(-2.f, __builtin_amdgcn_rcpf(1.f + __expf(2.f * v1)), 1.f);
    float w2 = fmaf(-2.f, __builtin_amdgcn_rcpf(1.f + __expf(2.f * v2)), 1.f);
    float w3 = fmaf(-2.f, __builtin_amdgcn_rcpf(1.f + __expf(2.f * v3)), 1.f);
    bool wr = (col == n);
    w0r = wr ? w0 : w0r;
    w1r = wr ? w1 : w1r;
    w2r = wr ? w2 : w2r;
    w3r = wr ? w3 : w3r;
    int src = (lane & 48) | n;
    float b0 = __shfl(w0, src);
    float b1 = __shfl(w1, src);
    float b2 = __shfl(w2, src);
    float b3 = __shfl(w3, src);
    if (col > n) {
      acc[0] = fmaf(b0, dv, acc[0]);
      acc[1] = fmaf(b1, dv, acc[1]);
      acc[2] = fmaf(b2, dv, acc[2]);
      acc[3] = fmaf(b3, dv, acc[3]);
    }
  }
  // persist this tile's w (each lane was writer exactly once, at n == col)
  wb[(quad * 4 + 0) * WSTRIDE + kt + col] = f2bf(w0r);
  wb[(quad * 4 + 1) * WSTRIDE + kt + col] = f2bf(w1r);
  wb[(quad * 4 + 2) * WSTRIDE + kt + col] = f2bf(w2r);
  wb[(quad * 4 + 3) * WSTRIDE + kt + col] = f2bf(w3r);
  // reload this tile's w into its A-fragment chunk (same-wave LDS, lgkmcnt-ordered)
  if ((quad >> 1) == (t & 1)) {
    constexpr int c = t >> 1;
    whiF[c] = *(const short8*)(wb + (lane & 15) * WSTRIDE + c * 32 + quad * 8);
  }
}

__global__ __launch_bounds__(256) void k_solve(const float* __restrict__ xu,
                                               const float* __restrict__ D11,
                                               const ushort* __restrict__ D11B,
                                               const float* __restrict__ lam,
                                               const float* __restrict__ bv,
                                               ushort* __restrict__ P) {
  __shared__ ushort wB[4][16 * WSTRIDE];   // per-wave bf16 w
  __shared__ float d11diag[16][16][17];    // all 16 diagonal D11 blocks
  const int tid = threadIdx.x;
  const int wave = tid >> 6, lane = tid & 63;
  const int col = lane & 15, quad = lane >> 4;
  const int r0w = blockIdx.x * 64 + wave * 16;
  for (int i = tid; i < 4096; i += 256) {
    int tt = i >> 8, r = (i >> 4) & 15, c = i & 15;
    d11diag[tt][r][c] = D11[(size_t)(tt * 16 + r) * NQq + tt * 16 + c];
  }
  Pre pre0, pre1;
  tile_loads<0>(xu, D11B, lam, bv, col, quad, r0w, pre0);
  __syncthreads();                          // the only block-wide barrier
  ushort* wb = &wB[wave][0];
  short8 whiF[8] = {};
  do_tile<0>(xu, D11B, lam, bv, wb, d11diag, whiF, lane, col, quad, r0w, pre0, pre1);
  do_tile<1>(xu, D11B, lam, bv, wb, d11diag, whiF, lane, col, quad, r0w, pre1, pre0);
  do_tile<2>(xu, D11B, lam, bv, wb, d11diag, whiF, lane, col, quad, r0w, pre0, pre1);
  do_tile<3>(xu, D11B, lam, bv, wb, d11diag, whiF, lane, col, quad, r0w, pre1, pre0);
  do_tile<4>(xu, D11B, lam, bv, wb, d11diag, whiF, lane, col, quad, r0w, pre0, pre1);
  do_tile<5>(xu, D11B, lam, bv, wb, d11diag, whiF, lane, col, quad, r0w, pre1, pre0);
  do_tile<6>(xu, D11B, lam, bv, wb, d11diag, whiF, lane, col, quad, r0w, pre0, pre1);
  do_tile<7>(xu, D11B, lam, bv, wb, d11diag, whiF, lane, col, quad, r0w, pre1, pre0);
  do_tile<8>(xu, D11B, lam, bv, wb, d11diag, whiF, lane, col, quad, r0w, pre0, pre1);
  do_tile<9>(xu, D11B, lam, bv, wb, d11diag, whiF, lane, col, quad, r0w, pre1, pre0);
  do_tile<10>(xu, D11B, lam, bv, wb, d11diag, whiF, lane, col, quad, r0w, pre0, pre1);
  do_tile<11>(xu, D11B, lam, bv, wb, d11diag, whiF, lane, col, quad, r0w, pre1, pre0);
  do_tile<12>(xu, D11B, lam, bv, wb, d11diag, whiF, lane, col, quad, r0w, pre0, pre1);
  do_tile<13>(xu, D11B, lam, bv, wb, d11diag, whiF, lane, col, quad, r0w, pre1, pre0);
  do_tile<14>(xu, D11B, lam, bv, wb, d11diag, whiF, lane, col, quad, r0w, pre0, pre1);
  do_tile<15>(xu, D11B, lam, bv, wb, d11diag, whiF, lane, col, quad, r0w, pre1, pre0);
  // write w rows (bf16) to P cols 512..767
  #pragma unroll
  for (int it = 0; it < 8; ++it) {
    int f = it * 64 + lane;
    int m = f >> 5, k8 = f & 31;
    uint4 v = *(const uint4*)(wb + m * WSTRIDE + k8 * 8);
    *(uint4*)(P + (size_t)(r0w + m) * KP + NXq + k8 * 8) = v;
  }
}

extern "C" void kernel_launch(void* const* d_in, const int* in_sizes, int n_in,
                              void* d_out, int out_size, void* d_ws, size_t ws_size,
                              hipStream_t stream) {
  const float* x   = (const float*)d_in[0];
  const float* u   = (const float*)d_in[1];
  const float* F   = (const float*)d_in[2];
  const float* B1  = (const float*)d_in[3];
  const float* B2  = (const float*)d_in[4];
  const float* C1  = (const float*)d_in[5];
  const float* C2  = (const float*)d_in[6];
  const float* D11 = (const float*)d_in[7];
  const float* D12 = (const float*)d_in[8];
  const float* D21 = (const float*)d_in[9];
  const float* E   = (const float*)d_in[10];
  const float* lam = (const float*)d_in[11];
  const float* bv  = (const float*)d_in[12];

  char* ws = (char*)d_ws;
  ushort* P    = (ushort*)ws;                                     // 32 MB
  float* xu    = (float*)(ws + (size_t)(32u << 20));              // 16 MB
  float* AUG0  = (float*)(ws + (size_t)(48u << 20));              // 3 MB
  float* AUG1  = (float*)(ws + (size_t)(52u << 20));              // 3 MB
  ushort* Wfull = (ushort*)(ws + (size_t)(56u << 20));            // 1.25 MB bf16
  ushort* Wxu   = (ushort*)(ws + (size_t)(58u << 20));            // 0.5 MB bf16
  ushort* D11B  = (ushort*)(ws + (size_t)(59u << 20));            // 128 KB bf16
  float* out   = (float*)d_out;
  float* AUGbuf[2] = { AUG0, AUG1 };

  k_prep<<<17152, 256, 0, stream>>>(x, u, E, F, B1, B2, C1, C2, D11, D12, D21,
                                    P, AUG0, Wxu, D11B, Wfull);
  for (int s = 0; s < 8; ++s)
    k_gj<<<dim3(8, 23 - s), 256, 0, stream>>>(AUGbuf[s & 1], AUGbuf[(s + 1) & 1],
                                              Wfull, s, s == 7);
  k_gemm<false><<<dim3(128, 2), 256, 0, stream>>>(P, Wxu, xu);    // xu = x@C1^T + u@D12^T
  k_solve<<<256, 256, 0, stream>>>(xu, D11, D11B, lam, bv, P);    // w -> P[:,512:768]
  k_gemm<true><<<dim3(128, 5), 256, 0, stream>>>(P, Wfull, out);  // dx, y
}

// Round 4
// 484.138 us; speedup vs baseline: 5.3760x; 1.6635x over previous
//
#include <hip/hip_runtime.h>

#define NBq 16384
#define NXq 512
#define NUq 256
#define NYq 128
#define NQq 256
#define KP  1024   // P width: [x(512) | w(256) | u(256)]
#define AUGW 1536  // [E(512) | F(512) | B1(256) | B2(256)]

typedef __attribute__((ext_vector_type(8))) short short8;
typedef __attribute__((ext_vector_type(4))) float f32x4;

__device__ __forceinline__ ushort f2bf(float f) {
  uint x = __float_as_uint(f);
  x += 0x7FFFu + ((x >> 16) & 1u);   // RNE
  return (ushort)(x >> 16);
}

// ---------------- fused prep: pack x,u -> P ; AUG ; Wxu ; D11B ; Wfull static rows ----------------
__global__ __launch_bounds__(256) void k_prep(const float* __restrict__ x, const float* __restrict__ u,
                                              const float* __restrict__ E, const float* __restrict__ F,
                                              const float* __restrict__ B1, const float* __restrict__ B2,
                                              const float* __restrict__ C1, const float* __restrict__ C2,
                                              const float* __restrict__ D11, const float* __restrict__ D12,
                                              const float* __restrict__ D21,
                                              ushort* __restrict__ P, float* __restrict__ AUG,
                                              ushort* __restrict__ Wxu, ushort* __restrict__ D11B,
                                              ushort* __restrict__ Wfull) {
  int b = blockIdx.x, tid = threadIdx.x;
  if (b < 12288) {                       // pack x,u (float4 -> bf16x4)
    int idx = b * 256 + tid;
    const int nx4 = NBq * NXq / 4;
    if (idx < nx4) {
      float4 v = *(const float4*)(x + (size_t)idx * 4);
      int row = idx >> 7, c4 = idx & 127;
      ushort4 h = { f2bf(v.x), f2bf(v.y), f2bf(v.z), f2bf(v.w) };
      *(ushort4*)(P + (size_t)row * KP + c4 * 4) = h;
    } else {
      int i = idx - nx4;
      float4 v = *(const float4*)(u + (size_t)i * 4);
      int row = i >> 6, c4 = i & 63;
      ushort4 h = { f2bf(v.x), f2bf(v.y), f2bf(v.z), f2bf(v.w) };
      *(ushort4*)(P + (size_t)row * KP + 768 + c4 * 4) = h;
    }
  } else if (b < 15360) {                // AUG = [E | F B1 B2]
    int idx = (b - 12288) * 256 + tid;
    int r = idx / AUGW, c = idx % AUGW;
    float v;
    if (c < 512)       v = E[r * 512 + c];
    else if (c < 1024) v = F[r * 512 + (c - 512)];
    else if (c < 1280) v = B1[r * 256 + (c - 1024)];
    else               v = B2[r * 256 + (c - 1280)];
    AUG[idx] = v;
  } else if (b < 16384) {                // Wxu = [C1 | 0 | D12] bf16
    int idx = (b - 15360) * 256 + tid;
    int r = idx >> 10, k = idx & 1023;
    float v;
    if (k < 512)      v = C1[r * 512 + k];
    else if (k < 768) v = 0.f;
    else              v = D12[r * 256 + (k - 768)];
    Wxu[idx] = f2bf(v);
  } else if (b < 16640) {                // D11 -> bf16
    int idx = (b - 16384) * 256 + tid;
    D11B[idx] = f2bf(D11[idx]);
  } else {                               // Wfull rows 512..639 = [C2 | D21 | 0]
    int idx = (b - 16640) * 256 + tid;   // < 131072
    int j = idx >> 10, k = idx & 1023;
    float v;
    if (k < 512)      v = C2[j * 512 + k];
    else if (k < 768) v = D21[j * 256 + (k - 512)];
    else              v = 0.f;
    Wfull[(size_t)(512 + j) * KP + k] = f2bf(v);
  }
}

// ---------------- fused blocked Gauss-Jordan step v2 (ping-pong) ----------------
// Per block: invert pivot 64x64 via 4 stages of 16-panel GJ (16x16 pivot in regs
// via shfl on wave 0, rank-16 elimination by all waves), then PB = Dinv@panel,
// out = A - MC@PB (pivot r-tile: out = PB). Last step emits Wfull bf16 directly.
__global__ __launch_bounds__(256) void k_gj(const float* __restrict__ Ain, float* __restrict__ Aout,
                                            ushort* __restrict__ Wfull, int s, int last) {
  __shared__ float M[64][132];    // [pivot 64x64 | inverse 64x64], b128-aligned rows
  __shared__ float sP[64][68];
  __shared__ float sMC[64][68];
  __shared__ float pinv[16][17];
  const int tid = threadIdx.x;
  const int wave = tid >> 6, lane = tid & 63;
  const int s64 = s * 64, r0 = blockIdx.x * 64, c0 = (s + 1 + blockIdx.y) * 64;
  const int r2 = tid >> 2, cq = (tid & 3) * 16;

  // ---- stage tiles (float4 coalesced) ----
  float av[16];
  #pragma unroll
  for (int c4 = 0; c4 < 4; ++c4) {
    float4 v = *(const float4*)(Ain + (size_t)(r0 + r2) * AUGW + c0 + cq + c4 * 4);
    av[c4 * 4 + 0] = v.x; av[c4 * 4 + 1] = v.y; av[c4 * 4 + 2] = v.z; av[c4 * 4 + 3] = v.w;
    *(float4*)(&sP[r2][cq + c4 * 4]) =
        *(const float4*)(Ain + (size_t)(s64 + r2) * AUGW + c0 + cq + c4 * 4);
    *(float4*)(&sMC[r2][cq + c4 * 4]) =
        *(const float4*)(Ain + (size_t)(r0 + r2) * AUGW + s64 + cq + c4 * 4);
    *(float4*)(&M[r2][cq + c4 * 4]) =
        *(const float4*)(Ain + (size_t)(s64 + r2) * AUGW + s64 + cq + c4 * 4);
  }
  #pragma unroll
  for (int c = 0; c < 16; ++c)
    M[r2][64 + cq + c] = (r2 == cq + c) ? 1.f : 0.f;
  __syncthreads();

  // ---- invert M (64x64) in place: 4 stages of 16-panel GJ ----
  for (int t = 0; t < 4; ++t) {
    const int kt = t * 16;
    // phase 1: wave 0 inverts 16x16 pivot in registers (lanes = columns of [P|I])
    if (wave == 0) {
      const int cc = lane & 31;
      float q[16];
      #pragma unroll
      for (int r = 0; r < 16; ++r)
        q[r] = (cc < 16) ? M[kt + r][kt + cc] : ((r == cc - 16) ? 1.f : 0.f);
      #pragma unroll
      for (int p = 0; p < 16; ++p) {
        float piv = __shfl(q[p], p);
        float rp = __builtin_amdgcn_rcpf(piv);
        rp = rp * (2.f - piv * rp);         // NR: fp32-exact reciprocal
        float a[16];
        #pragma unroll
        for (int r = 0; r < 16; ++r) a[r] = __shfl(q[r], p);
        q[p] *= rp;
        #pragma unroll
        for (int r = 0; r < 16; ++r)
          if (r != p) q[r] = fmaf(-a[r], q[p], q[r]);
      }
      if (lane >= 16 && lane < 32) {
        #pragma unroll
        for (int r = 0; r < 16; ++r) pinv[r][lane - 16] = q[r];
      }
    }
    __syncthreads();
    // phase 2: R = pinv @ M[kt:kt+16][0:128] (regs, then overwrite pivot rows)
    {
      const int ri = tid >> 4, j0 = (tid & 15) * 8;
      float rr[8] = {};
      #pragma unroll
      for (int k = 0; k < 16; ++k) {
        float pv = pinv[ri][k];
        #pragma unroll
        for (int c = 0; c < 8; ++c) rr[c] = fmaf(pv, M[kt + k][j0 + c], rr[c]);
      }
      __syncthreads();
      #pragma unroll
      for (int c = 0; c < 8; c += 4)
        *(float4*)(&M[kt + ri][j0 + c]) = make_float4(rr[c], rr[c+1], rr[c+2], rr[c+3]);
    }
    __syncthreads();
    // phase 3: eliminate rows r outside the pivot band; wave owns 32-col slice
    // (R-row reads are wave-uniform -> LDS broadcast)
    {
      const int r = lane, ch = wave * 32;
      const bool act = (r >> 4) != t;
      float mult[16], o2[32];
      if (act) {
        #pragma unroll
        for (int k = 0; k < 16; ++k) mult[k] = M[r][kt + k];
        #pragma unroll
        for (int c = 0; c < 32; c += 4) {
          float4 v = *(const float4*)(&M[r][ch + c]);
          o2[c] = v.x; o2[c+1] = v.y; o2[c+2] = v.z; o2[c+3] = v.w;
        }
      }
      __syncthreads();               // all pre-update reads done before writes
      if (act) {
        #pragma unroll
        for (int k = 0; k < 16; ++k) {
          float mk = mult[k];
          #pragma unroll
          for (int c = 0; c < 32; ++c) o2[c] = fmaf(-mk, M[kt + k][ch + c], o2[c]);
        }
        #pragma unroll
        for (int c = 0; c < 32; c += 4)
          *(float4*)(&M[r][ch + c]) = make_float4(o2[c], o2[c+1], o2[c+2], o2[c+3]);
      }
    }
    __syncthreads();
  }

  // ---- PB = Dinv @ sP (Dinv = M[:,64:128]) ----
  float pb[16] = {};
  #pragma unroll 4
  for (int q = 0; q < 64; ++q) {
    float dv = M[r2][64 + q];
    #pragma unroll
    for (int c = 0; c < 16; ++c) pb[c] = fmaf(dv, sP[q][cq + c], pb[c]);
  }
  __syncthreads();
  #pragma unroll
  for (int c = 0; c < 16; c += 4)
    *(float4*)(&sP[r2][cq + c]) = make_float4(pb[c], pb[c+1], pb[c+2], pb[c+3]);
  __syncthreads();

  // ---- out = av - MC @ PB  (pivot r-tile: out = PB) ----
  float o[16];
  if (blockIdx.x == (unsigned)s) {
    #pragma unroll
    for (int c = 0; c < 16; ++c) o[c] = pb[c];
  } else {
    #pragma unroll
    for (int c = 0; c < 16; ++c) o[c] = av[c];
    #pragma unroll 4
    for (int q = 0; q < 64; ++q) {
      float mc = sMC[r2][q];
      #pragma unroll
      for (int c = 0; c < 16; ++c) o[c] = fmaf(-mc, sP[q][cq + c], o[c]);
    }
  }
  if (last) {                       // G rows of Wfull (c0 >= 512 at s=7)
    int k0 = c0 - 512 + cq;
    #pragma unroll
    for (int c = 0; c < 16; c += 4) {
      ushort4 h = { f2bf(o[c]), f2bf(o[c+1]), f2bf(o[c+2]), f2bf(o[c+3]) };
      *(ushort4*)(Wfull + (size_t)(r0 + r2) * KP + k0 + c) = h;
    }
  } else {
    #pragma unroll
    for (int c = 0; c < 16; c += 4)
      *(float4*)(Aout + (size_t)(r0 + r2) * AUGW + c0 + cq + c) =
          make_float4(o[c], o[c+1], o[c+2], o[c+3]);
  }
}

// ---------------- bf16 MFMA GEMM: out[m][n] = sum_k P[m][k] * W[n][k] ----------------
template<bool SPLIT>
__global__ __launch_bounds__(256) void k_gemm(const ushort* __restrict__ P, const ushort* __restrict__ W,
                                              float* __restrict__ out) {
  __shared__ ushort sA[128 * 32];
  __shared__ ushort sB[128 * 32];
  int tid = threadIdx.x;
  int lane = tid & 63, wave = tid >> 6;
  int wm = wave & 1, wn = wave >> 1;
  int m0 = blockIdx.x * 128;
  int n0 = blockIdx.y * 128;
  int r16 = lane & 15, kq = lane >> 4;
  f32x4 acc[4][4] = {};
  for (int kb = 0; kb < KP / 32; ++kb) {
    #pragma unroll
    for (int j = 0; j < 2; ++j) {
      int i = tid + j * 256;
      int row = i >> 2, seg = i & 3;
      *(uint4*)(&sA[row * 32 + seg * 8]) =
          *(const uint4*)(P + (size_t)(m0 + row) * KP + kb * 32 + seg * 8);
      *(uint4*)(&sB[row * 32 + seg * 8]) =
          *(const uint4*)(W + (size_t)(n0 + row) * KP + kb * 32 + seg * 8);
    }
    __syncthreads();
    short8 af[4], bf[4];
    #pragma unroll
    for (int t = 0; t < 4; ++t) {
      af[t] = *(const short8*)(&sA[(wm * 64 + t * 16 + r16) * 32 + kq * 8]);
      bf[t] = *(const short8*)(&sB[(wn * 64 + t * 16 + r16) * 32 + kq * 8]);
    }
    #pragma unroll
    for (int mt = 0; mt < 4; ++mt)
      #pragma unroll
      for (int nt = 0; nt < 4; ++nt)
        acc[mt][nt] = __builtin_amdgcn_mfma_f32_16x16x32_bf16(af[mt], bf[nt], acc[mt][nt], 0, 0, 0);
    __syncthreads();
  }
  #pragma unroll
  for (int mt = 0; mt < 4; ++mt)
    #pragma unroll
    for (int nt = 0; nt < 4; ++nt)
      #pragma unroll
      for (int i = 0; i < 4; ++i) {
        int m = m0 + wm * 64 + mt * 16 + kq * 4 + i;
        int n = n0 + wn * 64 + nt * 16 + r16;
        float val = acc[mt][nt][i];
        if (SPLIT) {
          if (n < NXq) out[(size_t)m * NXq + n] = val;
          else out[(size_t)NBq * NXq + (size_t)m * NYq + (n - NXq)] = val;
        } else {
          out[(size_t)m * NQq + n] = val;
        }
      }
}

// ---------------- MFMA-blocked tanh forward substitution (barrier-free main loop) ----------------
#define WSTRIDE 264

struct Pre {
  f32x4 xuv;
  short8 b[8];
  float rl, bvrl;
};

template<int t>
__device__ __forceinline__ void tile_loads(const float* __restrict__ xu,
                                           const ushort* __restrict__ D11B,
                                           const float* __restrict__ lam,
                                           const float* __restrict__ bv,
                                           int col, int quad, int r0w, Pre& pre) {
  constexpr int kt = t * 16;
  constexpr int cmax = (t + 1) >> 1;
  #pragma unroll
  for (int i = 0; i < 4; ++i)
    pre.xuv[i] = xu[(size_t)(r0w + quad * 4 + i) * NQq + kt + col];
  #pragma unroll
  for (int c = 0; c < cmax; ++c)
    pre.b[c] = *(const short8*)(D11B + (size_t)(kt + col) * NQq + c * 32 + quad * 8);
  float l = lam[kt + col];
  pre.rl = 1.0f / l;
  pre.bvrl = bv[kt + col] * pre.rl;
}

template<int t>
__device__ __forceinline__ void do_tile(const float* __restrict__ xu,
                                        const ushort* __restrict__ D11B,
                                        const float* __restrict__ lam,
                                        const float* __restrict__ bv,
                                        ushort* wb, const float (*d11diag)[16][17],
                                        short8 (&whiF)[8], int lane, int col, int quad,
                                        int r0w, Pre& cur, Pre& nxt) {
  constexpr int kt = t * 16;
  constexpr int cmax = (t + 1) >> 1;
  if constexpr (t < 15)
    tile_loads<t + 1>(xu, D11B, lam, bv, col, quad, r0w, nxt);
  f32x4 acc = cur.xuv;
  #pragma unroll
  for (int c = 0; c < cmax; ++c)
    acc = __builtin_amdgcn_mfma_f32_16x16x32_bf16(whiF[c], cur.b[c], acc, 0, 0, 0);
  const float rl = cur.rl, bvrl = cur.bvrl;
  float w0r = 0.f, w1r = 0.f, w2r = 0.f, w3r = 0.f;
  #pragma unroll
  for (int n = 0; n < 16; ++n) {
    float dv = d11diag[t][col][n];
    float v0 = fmaf(acc[0], rl, bvrl);
    float v1 = fmaf(acc[1], rl, bvrl);
    float v2 = fmaf(acc[2], rl, bvrl);
    float v3 = fmaf(acc[3], rl, bvrl);
    float w0 = fmaf(-2.f, __builtin_amdgcn_rcpf(1.f + __expf(2.f * v0)), 1.f);
    float w1 = fmaf(-2.f, __builtin_amdgcn_rcpf(1.f + __expf(2.f * v1)), 1.f);
    float w2 = fmaf(-2.f, __builtin_amdgcn_rcpf(1.f + __expf(2.f * v2)), 1.f);
    float w3 = fmaf(-2.f, __builtin_amdgcn_rcpf(1.f + __expf(2.f * v3)), 1.f);
    bool wr = (col == n);
    w0r = wr ? w0 : w0r;
    w1r = wr ? w1 : w1r;
    w2r = wr ? w2 : w2r;
    w3r = wr ? w3 : w3r;
    int src = (lane & 48) | n;
    float b0 = __shfl(w0, src);
    float b1 = __shfl(w1, src);
    float b2 = __shfl(w2, src);
    float b3 = __shfl(w3, src);
    if (col > n) {
      acc[0] = fmaf(b0, dv, acc[0]);
      acc[1] = fmaf(b1, dv, acc[1]);
      acc[2] = fmaf(b2, dv, acc[2]);
      acc[3] = fmaf(b3, dv, acc[3]);
    }
  }
  wb[(quad * 4 + 0) * WSTRIDE + kt + col] = f2bf(w0r);
  wb[(quad * 4 + 1) * WSTRIDE + kt + col] = f2bf(w1r);
  wb[(quad * 4 + 2) * WSTRIDE + kt + col] = f2bf(w2r);
  wb[(quad * 4 + 3) * WSTRIDE + kt + col] = f2bf(w3r);
  if ((quad >> 1) == (t & 1)) {
    constexpr int c = t >> 1;
    whiF[c] = *(const short8*)(wb + (lane & 15) * WSTRIDE + c * 32 + quad * 8);
  }
}

__global__ __launch_bounds__(256) void k_solve(const float* __restrict__ xu,
                                               const float* __restrict__ D11,
                                               const ushort* __restrict__ D11B,
                                               const float* __restrict__ lam,
                                               const float* __restrict__ bv,
                                               ushort* __restrict__ P) {
  __shared__ ushort wB[4][16 * WSTRIDE];   // per-wave bf16 w
  __shared__ float d11diag[16][16][17];    // all 16 diagonal D11 blocks
  const int tid = threadIdx.x;
  const int wave = tid >> 6, lane = tid & 63;
  const int col = lane & 15, quad = lane >> 4;
  const int r0w = blockIdx.x * 64 + wave * 16;
  for (int i = tid; i < 4096; i += 256) {
    int tt = i >> 8, r = (i >> 4) & 15, c = i & 15;
    d11diag[tt][r][c] = D11[(size_t)(tt * 16 + r) * NQq + tt * 16 + c];
  }
  Pre pre0, pre1;
  tile_loads<0>(xu, D11B, lam, bv, col, quad, r0w, pre0);
  __syncthreads();                          // the only block-wide barrier
  ushort* wb = &wB[wave][0];
  short8 whiF[8] = {};
  do_tile<0>(xu, D11B, lam, bv, wb, d11diag, whiF, lane, col, quad, r0w, pre0, pre1);
  do_tile<1>(xu, D11B, lam, bv, wb, d11diag, whiF, lane, col, quad, r0w, pre1, pre0);
  do_tile<2>(xu, D11B, lam, bv, wb, d11diag, whiF, lane, col, quad, r0w, pre0, pre1);
  do_tile<3>(xu, D11B, lam, bv, wb, d11diag, whiF, lane, col, quad, r0w, pre1, pre0);
  do_tile<4>(xu, D11B, lam, bv, wb, d11diag, whiF, lane, col, quad, r0w, pre0, pre1);
  do_tile<5>(xu, D11B, lam, bv, wb, d11diag, whiF, lane, col, quad, r0w, pre1, pre0);
  do_tile<6>(xu, D11B, lam, bv, wb, d11diag, whiF, lane, col, quad, r0w, pre0, pre1);
  do_tile<7>(xu, D11B, lam, bv, wb, d11diag, whiF, lane, col, quad, r0w, pre1, pre0);
  do_tile<8>(xu, D11B, lam, bv, wb, d11diag, whiF, lane, col, quad, r0w, pre0, pre1);
  do_tile<9>(xu, D11B, lam, bv, wb, d11diag, whiF, lane, col, quad, r0w, pre1, pre0);
  do_tile<10>(xu, D11B, lam, bv, wb, d11diag, whiF, lane, col, quad, r0w, pre0, pre1);
  do_tile<11>(xu, D11B, lam, bv, wb, d11diag, whiF, lane, col, quad, r0w, pre1, pre0);
  do_tile<12>(xu, D11B, lam, bv, wb, d11diag, whiF, lane, col, quad, r0w, pre0, pre1);
  do_tile<13>(xu, D11B, lam, bv, wb, d11diag, whiF, lane, col, quad, r0w, pre1, pre0);
  do_tile<14>(xu, D11B, lam, bv, wb, d11diag, whiF, lane, col, quad, r0w, pre0, pre1);
  do_tile<15>(xu, D11B, lam, bv, wb, d11diag, whiF, lane, col, quad, r0w, pre1, pre0);
  #pragma unroll
  for (int it = 0; it < 8; ++it) {
    int f = it * 64 + lane;
    int m = f >> 5, k8 = f & 31;
    uint4 v = *(const uint4*)(wb + m * WSTRIDE + k8 * 8);
    *(uint4*)(P + (size_t)(r0w + m) * KP + NXq + k8 * 8) = v;
  }
}

extern "C" void kernel_launch(void* const* d_in, const int* in_sizes, int n_in,
                              void* d_out, int out_size, void* d_ws, size_t ws_size,
                              hipStream_t stream) {
  const float* x   = (const float*)d_in[0];
  const float* u   = (const float*)d_in[1];
  const float* F   = (const float*)d_in[2];
  const float* B1  = (const float*)d_in[3];
  const float* B2  = (const float*)d_in[4];
  const float* C1  = (const float*)d_in[5];
  const float* C2  = (const float*)d_in[6];
  const float* D11 = (const float*)d_in[7];
  const float* D12 = (const float*)d_in[8];
  const float* D21 = (const float*)d_in[9];
  const float* E   = (const float*)d_in[10];
  const float* lam = (const float*)d_in[11];
  const float* bv  = (const float*)d_in[12];

  char* ws = (char*)d_ws;
  ushort* P    = (ushort*)ws;                                     // 32 MB
  float* xu    = (float*)(ws + (size_t)(32u << 20));              // 16 MB
  float* AUG0  = (float*)(ws + (size_t)(48u << 20));              // 3 MB
  float* AUG1  = (float*)(ws + (size_t)(52u << 20));              // 3 MB
  ushort* Wfull = (ushort*)(ws + (size_t)(56u << 20));            // 1.25 MB bf16
  ushort* Wxu   = (ushort*)(ws + (size_t)(58u << 20));            // 0.5 MB bf16
  ushort* D11B  = (ushort*)(ws + (size_t)(59u << 20));            // 128 KB bf16
  float* out   = (float*)d_out;
  float* AUGbuf[2] = { AUG0, AUG1 };

  k_prep<<<17152, 256, 0, stream>>>(x, u, E, F, B1, B2, C1, C2, D11, D12, D21,
                                    P, AUG0, Wxu, D11B, Wfull);
  for (int s = 0; s < 8; ++s)
    k_gj<<<dim3(8, 23 - s), 256, 0, stream>>>(AUGbuf[s & 1], AUGbuf[(s + 1) & 1],
                                              Wfull, s, s == 7);
  k_gemm<false><<<dim3(128, 2), 256, 0, stream>>>(P, Wxu, xu);    // xu = x@C1^T + u@D12^T
  k_solve<<<256, 256, 0, stream>>>(xu, D11, D11B, lam, bv, P);    // w -> P[:,512:768]
  k_gemm<true><<<dim3(128, 5), 256, 0, stream>>>(P, Wfull, out);  // dx, y
}